// Round 7
// baseline (779.743 us; speedup 1.0000x reference)
//
#include <hip/hip_runtime.h>
#include <hip/hip_bf16.h>

__device__ __forceinline__ float sigf(float x){ return __builtin_amdgcn_rcpf(1.f+__expf(-x)); }
__device__ __forceinline__ float tanhfa(float x){
  return 1.f - 2.f*__builtin_amdgcn_rcpf(1.f + __expf(2.f*x));
}

#define ALPHA 0.2f
#define NEGV  -9e15f

// N=256 nodes, S=64 sensors, W=256 window, H=32 hidden. All fp32.

__device__ __forceinline__ void gl2lds16(const float* g, float* l){
  __builtin_amdgcn_global_load_lds(
      (const __attribute__((address_space(1))) void*)g,
      (__attribute__((address_space(3))) void*)l, 16, 0, 0);
}

// ---- k_mask: pack adjacency fp32 (0/1) -> bitmask via wave ballot ----
__global__ __launch_bounds__(256) void k_mask(const float* __restrict__ src,
                                              unsigned* __restrict__ dst, int nelem){
  const int stride = gridDim.x * blockDim.x;
  const int lane = threadIdx.x & 63;
  for (int e = blockIdx.x*blockDim.x + threadIdx.x; e < nelem; e += stride){
    unsigned long long m = __ballot(src[e] > 0.f);
    if (lane == 0)       dst[e >> 5] = (unsigned)m;
    else if (lane == 32) dst[e >> 5] = (unsigned)(m >> 32);
  }
}

// ---- k3: Wh_T + Tf1/Tf2 partials. grid 512 = n*2 + c-half ----
// WhTt stored i-major: WhTt[n][i][64 c] (k4 stages [j][c] tiles linearly).
__global__ __launch_bounds__(256) void k3_wht(const float* __restrict__ x,
                                              const float* __restrict__ TW,
                                              const float* __restrict__ Ta,
                                              float* __restrict__ WhTt,
                                              float* __restrict__ Tf1p,
                                              float* __restrict__ Tf2p){
  const int n = blockIdx.x >> 1, ch = blockIdx.x & 1, c0 = ch*32;
  const int tid = threadIdx.x;
  __shared__ float Wm[64][36];
  __shared__ float as1[32], as2[32];
  for (int idx = tid; idx < 2048; idx += 256){
    int k = idx >> 5, cc = idx & 31;
    Wm[k][cc] = TW[n*4096 + k*64 + c0 + cc];
  }
  if (tid < 32){ as1[tid] = Ta[n*128 + c0 + tid]; as2[tid] = Ta[n*128 + 64 + c0 + tid]; }
  __syncthreads();
  const int i = tid;
  const float* xn = x + n*16384;
  float acc[32];
#pragma unroll
  for (int c = 0; c < 32; ++c) acc[c] = 0.f;
#pragma unroll 2
  for (int k = 0; k < 64; ++k){
    float xv = xn[k*256 + i];                  // coalesced
    const float* wr = &Wm[k][0];               // broadcast b128
#pragma unroll
    for (int c = 0; c < 32; ++c) acc[c] = fmaf(xv, wr[c], acc[c]);
  }
  float f1 = 0.f, f2 = 0.f;
#pragma unroll
  for (int c = 0; c < 32; ++c){ f1 = fmaf(acc[c], as1[c], f1); f2 = fmaf(acc[c], as2[c], f2); }
  Tf1p[ch*65536 + n*256 + i] = f1;
  Tf2p[ch*65536 + n*256 + i] = f2;
  float* o = WhTt + n*16384 + i*64 + c0;       // i-major store
#pragma unroll
  for (int q = 0; q < 8; ++q)
    *(float4*)&o[4*q] = make_float4(acc[4*q], acc[4*q+1], acc[4*q+2], acc[4*q+3]);
}

// ---- k4: time-GAT attention, two-phase register-tiled PV. grid 512 = n*2+ch ----
__global__ __launch_bounds__(256) void k4_tat(const float* __restrict__ WhTt,
                                              const float* __restrict__ Tf1p,
                                              const float* __restrict__ Tf2p,
                                              const unsigned* __restrict__ maskT,
                                              float* __restrict__ TatT){
  const int n = blockIdx.x >> 1, ch = blockIdx.x & 1, c0 = ch*32;
  const int tid = threadIdx.x;
  __shared__ float wtL[8192];                  // [256 j][32 c], 32 KB
  __shared__ float ptb[8192];                  // [32 jj][256 i], 32 KB
  __shared__ float f2s[256];
  __shared__ float ssum[256];
  __shared__ float wmax[4];
  {                                            // stage wt: lane = (row l>>3, quad l&7)
    const int w = tid >> 6, l = tid & 63;
    const float* src = WhTt + n*16384 + (w*64 + (l>>3))*64 + c0 + (l&7)*4;
    float* dst = &wtL[w*2048];
#pragma unroll
    for (int r = 0; r < 8; ++r) gl2lds16(src + r*512, dst + r*256);
  }
  const float f1  = Tf1p[n*256 + tid] + Tf1p[65536 + n*256 + tid];
  const float f2v = Tf2p[n*256 + tid] + Tf2p[65536 + n*256 + tid];
  f2s[tid] = f2v;
  unsigned mw[8];
#pragma unroll
  for (int w = 0; w < 8; ++w) mw[w] = maskT[n*2048 + tid*8 + w];
  float wm = f2v;
#pragma unroll
  for (int d = 1; d < 64; d <<= 1) wm = fmaxf(wm, __shfl_xor(wm, d));
  if ((tid & 63) == 0) wmax[tid >> 6] = wm;
  asm volatile("s_waitcnt vmcnt(0)" ::: "memory");
  __syncthreads();
  const float mb = fmaxf(fmaxf(wmax[0], wmax[1]), fmaxf(wmax[2], wmax[3]));
  const float tm = f1 + mb;
  const float m  = (tm > 0.f) ? tm : ALPHA*tm;
  const int iq = tid & 63, cq = tid >> 6;
  float acc[4][8];
#pragma unroll
  for (int r = 0; r < 4; ++r)
#pragma unroll
    for (int c = 0; c < 8; ++c) acc[r][c] = 0.f;
  float sloc = 0.f;
  for (int jt = 0; jt < 8; ++jt){
    const int j0 = jt*32;
    // ---- phase A: P-tile row tid ----
#pragma unroll
    for (int jj = 0; jj < 32; jj += 4){
      const float4 f2q = *(const float4*)&f2s[j0 + jj];
      const unsigned mk = mw[(j0 + jj) >> 5];
      const int sh = (j0 + jj) & 31;
      float t0 = f1 + f2q.x; t0 = (t0 > 0.f) ? t0 : ALPHA*t0;
      float t1 = f1 + f2q.y; t1 = (t1 > 0.f) ? t1 : ALPHA*t1;
      float t2 = f1 + f2q.z; t2 = (t2 > 0.f) ? t2 : ALPHA*t2;
      float t3 = f1 + f2q.w; t3 = (t3 > 0.f) ? t3 : ALPHA*t3;
      const float e0 = ((mk >> (sh+0)) & 1u) ? __expf(t0 - m) : 0.f;
      const float e1 = ((mk >> (sh+1)) & 1u) ? __expf(t1 - m) : 0.f;
      const float e2 = ((mk >> (sh+2)) & 1u) ? __expf(t2 - m) : 0.f;
      const float e3 = ((mk >> (sh+3)) & 1u) ? __expf(t3 - m) : 0.f;
      sloc += (e0 + e1) + (e2 + e3);
      ptb[(jj+0)*256 + tid] = e0;
      ptb[(jj+1)*256 + tid] = e1;
      ptb[(jj+2)*256 + tid] = e2;
      ptb[(jj+3)*256 + tid] = e3;
    }
    __syncthreads();
    // ---- phase B: acc[4 rows][8 c] ----
#pragma unroll 4
    for (int jj = 0; jj < 32; ++jj){
      const float4 p4 = *(const float4*)&ptb[jj*256 + 4*iq];      // distinct lanes
      const float4 w0 = *(const float4*)&wtL[(j0+jj)*32 + cq*8];  // broadcast
      const float4 w1 = *(const float4*)&wtL[(j0+jj)*32 + cq*8 + 4];
#pragma unroll
      for (int r = 0; r < 4; ++r){
        const float pv = (r == 0) ? p4.x : (r == 1) ? p4.y : (r == 2) ? p4.z : p4.w;
        acc[r][0] = fmaf(pv, w0.x, acc[r][0]);
        acc[r][1] = fmaf(pv, w0.y, acc[r][1]);
        acc[r][2] = fmaf(pv, w0.z, acc[r][2]);
        acc[r][3] = fmaf(pv, w0.w, acc[r][3]);
        acc[r][4] = fmaf(pv, w1.x, acc[r][4]);
        acc[r][5] = fmaf(pv, w1.y, acc[r][5]);
        acc[r][6] = fmaf(pv, w1.z, acc[r][6]);
        acc[r][7] = fmaf(pv, w1.w, acc[r][7]);
      }
    }
    __syncthreads();
  }
  ssum[tid] = sloc;
  __syncthreads();
  float* o = TatT + n*16384;
#pragma unroll
  for (int r = 0; r < 4; ++r){
    const int i2 = 4*iq + r;
    const float sv = ssum[i2];
    const float inv = (sv > 0.f) ? __builtin_amdgcn_rcpf(sv) : 0.f;
#pragma unroll
    for (int cc = 0; cc < 8; ++cc)
      o[(c0 + cq*8 + cc)*256 + i2] = acc[r][cc] * inv;
  }
}

// ---- k1: Wh_F = x @ Fatt_W. grid 512 = n*2 + c-half(128), block 256 ----
__global__ __launch_bounds__(256) void k1_whf(const float* __restrict__ x,
                                              const float* __restrict__ FW,
                                              float* __restrict__ WhF){
  const int n = blockIdx.x >> 1, ch = blockIdx.x & 1, c0 = ch*128;
  const int tid = threadIdx.x;
  __shared__ float xt[16384];                  // [i][k] linear, 64 KB
  {
    const int w = tid >> 6, l = tid & 63;
    const float* xg = x + n*16384 + w*4096 + l*4;
    float* ld = &xt[w*4096];
#pragma unroll
    for (int j = 0; j < 16; ++j) gl2lds16(xg + j*256, ld + j*256);
  }
  asm volatile("s_waitcnt vmcnt(0)" ::: "memory");
  __syncthreads();
  const int cq = tid & 31, iq = tid >> 5;      // c-quad, i-group(8 rows)
  const int cc = c0 + cq*4;
  const float* Wn = FW + (size_t)n*65536 + cc;
  const float* xrow = &xt[iq*8*256];
  float acc[8][4];
#pragma unroll
  for (int i = 0; i < 8; ++i)
#pragma unroll
    for (int c = 0; c < 4; ++c) acc[i][c] = 0.f;
#pragma unroll 2
  for (int k4 = 0; k4 < 64; ++k4){
    const float4 w0 = *(const float4*)&Wn[(4*k4+0)*256];
    const float4 w1 = *(const float4*)&Wn[(4*k4+1)*256];
    const float4 w2 = *(const float4*)&Wn[(4*k4+2)*256];
    const float4 w3 = *(const float4*)&Wn[(4*k4+3)*256];
#pragma unroll
    for (int i = 0; i < 8; ++i){
      const float4 xv = *(const float4*)&xrow[i*256 + 4*k4];
      acc[i][0] = fmaf(xv.x, w0.x, acc[i][0]); acc[i][0] = fmaf(xv.y, w1.x, acc[i][0]);
      acc[i][0] = fmaf(xv.z, w2.x, acc[i][0]); acc[i][0] = fmaf(xv.w, w3.x, acc[i][0]);
      acc[i][1] = fmaf(xv.x, w0.y, acc[i][1]); acc[i][1] = fmaf(xv.y, w1.y, acc[i][1]);
      acc[i][1] = fmaf(xv.z, w2.y, acc[i][1]); acc[i][1] = fmaf(xv.w, w3.y, acc[i][1]);
      acc[i][2] = fmaf(xv.x, w0.z, acc[i][2]); acc[i][2] = fmaf(xv.y, w1.z, acc[i][2]);
      acc[i][2] = fmaf(xv.z, w2.z, acc[i][2]); acc[i][2] = fmaf(xv.w, w3.z, acc[i][2]);
      acc[i][3] = fmaf(xv.x, w0.w, acc[i][3]); acc[i][3] = fmaf(xv.y, w1.w, acc[i][3]);
      acc[i][3] = fmaf(xv.z, w2.w, acc[i][3]); acc[i][3] = fmaf(xv.w, w3.w, acc[i][3]);
    }
  }
  float* o = WhF + n*16384 + cc;
#pragma unroll
  for (int i = 0; i < 8; ++i)
    *(float4*)&o[(iq*8 + i)*256] = make_float4(acc[i][0], acc[i][1], acc[i][2], acc[i][3]);
}

// ---- k2: feature-GAT softmax + Fat = att @ Wh. grid 256, block 512 (i-split) ----
__global__ __launch_bounds__(512) void k2_fat(const float* __restrict__ WhF,
                                              const float* __restrict__ Fa,
                                              const float* __restrict__ Fadj,
                                              float* __restrict__ Fat){
  const int n = blockIdx.x, tid = threadIdx.x;
  __shared__ float attT[64][68];               // attT[j][i]
  __shared__ float f1s[64], f2s[64];
  __shared__ float part[64][8][2];
  const float* Wh = WhF + n*16384;
  { // f1/f2: thread (i=tid>>3, q=tid&7) partial over 32 cols
    int i = tid >> 3, q = tid & 7;
    const float* an = Fa + n*512;
    float p1 = 0.f, p2 = 0.f;
    for (int cc = 0; cc < 32; ++cc){
      int c2 = q*32 + cc;
      float w = Wh[i*256 + c2];
      p1 = fmaf(w, an[c2], p1);
      p2 = fmaf(w, an[256 + c2], p2);
    }
    part[i][q][0] = p1; part[i][q][1] = p2;
  }
  __syncthreads();
  if (tid < 64){
    float s1 = 0.f, s2 = 0.f;
#pragma unroll
    for (int q = 0; q < 8; ++q){ s1 += part[tid][q][0]; s2 += part[tid][q][1]; }
    f1s[tid] = s1; f2s[tid] = s2;
  }
  __syncthreads();
  if (tid < 64){                               // masked softmax row -> attT column
    const int r = tid;
    const float f1 = f1s[r];
    const float* adjr = Fadj + n*4096 + r*64;
    unsigned m0 = 0, m1 = 0;
#pragma unroll
    for (int j = 0; j < 32; ++j) if (adjr[j] > 0.f) m0 |= (1u << j);
#pragma unroll
    for (int j = 0; j < 32; ++j) if (adjr[32+j] > 0.f) m1 |= (1u << j);
    float m = -INFINITY;
#pragma unroll
    for (int j = 0; j < 64; ++j){
      float e = f1 + f2s[j]; e = (e > 0.f) ? e : ALPHA*e;
      unsigned bit = (j < 32) ? ((m0 >> j) & 1u) : ((m1 >> (j-32)) & 1u);
      e = bit ? e : NEGV;
      m = fmaxf(m, e);
    }
    float s = 0.f;
#pragma unroll
    for (int j = 0; j < 64; ++j){
      float e = f1 + f2s[j]; e = (e > 0.f) ? e : ALPHA*e;
      unsigned bit = (j < 32) ? ((m0 >> j) & 1u) : ((m1 >> (j-32)) & 1u);
      e = bit ? e : NEGV;
      s += __expf(e - m);
    }
    const float inv = 1.f / s;
#pragma unroll
    for (int j = 0; j < 64; ++j){
      float e = f1 + f2s[j]; e = (e > 0.f) ? e : ALPHA*e;
      unsigned bit = (j < 32) ? ((m0 >> j) & 1u) : ((m1 >> (j-32)) & 1u);
      e = bit ? e : NEGV;
      attT[j][r] = __expf(e - m) * inv;
    }
  }
  __syncthreads();
  const int c = tid & 255, ih = tid >> 8;      // ih: 32-row half of output
  float acc[32];
#pragma unroll
  for (int i = 0; i < 32; ++i) acc[i] = 0.f;
#pragma unroll 2
  for (int j = 0; j < 64; ++j){
    float w = Wh[j*256 + c];                   // coalesced, L2-hot
    const float* ar = &attT[j][ih*32];         // broadcast b128 (16B-aligned)
#pragma unroll
    for (int i = 0; i < 32; ++i) acc[i] = fmaf(ar[i], w, acc[i]);
  }
  float* o = Fat + n*16384;
#pragma unroll
  for (int i = 0; i < 32; ++i) o[(ih*32 + i)*256 + c] = acc[i];
}

// ---- k5: partial Gi0 = cat_seg @ Wih0_seg^T. grid 768 = s*256 + n, block 128 ----
// v4: both tiles in LDS (broadcast reads), row-padded [.][36] so ALL reads are
// conflict-free; reg-staged dbuf (T14 issue-early/write-late, coalesced maps).
// Thread = (b: 12-gate group, ta: t-quad) -> tile 12g x 4t, acc 48.
// Per k4: 12 W + 4 cat b128 reads feed 192 FMA (2.3x fewer LDS instr than R5).
__global__ __launch_bounds__(128, 1) void k5_gi0(const float* __restrict__ Fat,
                                                 const float* __restrict__ TatT,
                                                 const float* __restrict__ x,
                                                 const float* __restrict__ Wih0,
                                                 float* __restrict__ P0,
                                                 float* __restrict__ P1,
                                                 float* __restrict__ P2){
  const int n = blockIdx.x & 255, s = blockIdx.x >> 8;
  const int tid = threadIdx.x;
  const int b = tid >> 4, ta = tid & 15;       // gate group (12 g), t-quad
  __shared__ float wl[2][3456];                // W  [96][36] pad, dbuf, 27.6 KB
  __shared__ float cl[2][2304];                // cat [64][36] pad, dbuf, 18.4 KB
  const float* src = (s == 0) ? (Fat + n*16384)
                   : (s == 1) ? (TatT + n*16384)
                              : (x + n*16384);
  const float* Wseg = Wih0 + (size_t)n*73728 + s*256;
  float4 wreg[6], creg[4];
  // ---- prologue: stage kt=0 (qid = j*128+tid; row = qid>>3, quad = qid&7) ----
#pragma unroll
  for (int j = 0; j < 6; ++j){
    const int qid = j*128 + tid, row = qid >> 3, q = qid & 7;
    wreg[j] = *(const float4*)(Wseg + (size_t)row*768 + q*4);
  }
#pragma unroll
  for (int j = 0; j < 4; ++j){
    const int qid = j*128 + tid, row = qid >> 3, q = qid & 7;
    creg[j] = *(const float4*)(src + row*256 + q*4);
  }
#pragma unroll
  for (int j = 0; j < 6; ++j){
    const int qid = j*128 + tid, row = qid >> 3, q = qid & 7;
    *(float4*)&wl[0][row*36 + q*4] = wreg[j];
  }
#pragma unroll
  for (int j = 0; j < 4; ++j){
    const int qid = j*128 + tid, row = qid >> 3, q = qid & 7;
    *(float4*)&cl[0][row*36 + q*4] = creg[j];
  }
  __syncthreads();
  float acc[12][4];
#pragma unroll
  for (int gi = 0; gi < 12; ++gi)
#pragma unroll
    for (int r = 0; r < 4; ++r) acc[gi][r] = 0.f;
#pragma unroll 1
  for (int kt = 0; kt < 8; ++kt){
    const int buf = kt & 1;
    if (kt < 7){                               // issue next-tile loads early (T14)
#pragma unroll
      for (int j = 0; j < 6; ++j){
        const int qid = j*128 + tid, row = qid >> 3, q = qid & 7;
        wreg[j] = *(const float4*)(Wseg + (size_t)row*768 + (kt+1)*32 + q*4);
      }
#pragma unroll
      for (int j = 0; j < 4; ++j){
        const int qid = j*128 + tid, row = qid >> 3, q = qid & 7;
        creg[j] = *(const float4*)(src + row*256 + (kt+1)*32 + q*4);
      }
    }
    const float* wb = &wl[buf][b*432];         // b*12*36
    const float* cb = &cl[buf][ta*144];        // ta*4*36
#pragma unroll
    for (int k4 = 0; k4 < 8; ++k4){
      float4 wv[12];
#pragma unroll
      for (int gi = 0; gi < 12; ++gi)
        wv[gi] = *(const float4*)(wb + gi*36 + k4*4);        // 4 addrs/wave, banks apart
      const float4 c0 = *(const float4*)(cb + 0*36 + k4*4);  // 16 addrs, 2-way free
      const float4 c1 = *(const float4*)(cb + 1*36 + k4*4);
      const float4 c2 = *(const float4*)(cb + 2*36 + k4*4);
      const float4 c3 = *(const float4*)(cb + 3*36 + k4*4);
#pragma unroll
      for (int gi = 0; gi < 12; ++gi){
        float a0 = acc[gi][0], a1 = acc[gi][1], a2 = acc[gi][2], a3 = acc[gi][3];
        a0 = fmaf(wv[gi].x, c0.x, a0); a1 = fmaf(wv[gi].x, c1.x, a1);
        a2 = fmaf(wv[gi].x, c2.x, a2); a3 = fmaf(wv[gi].x, c3.x, a3);
        a0 = fmaf(wv[gi].y, c0.y, a0); a1 = fmaf(wv[gi].y, c1.y, a1);
        a2 = fmaf(wv[gi].y, c2.y, a2); a3 = fmaf(wv[gi].y, c3.y, a3);
        a0 = fmaf(wv[gi].z, c0.z, a0); a1 = fmaf(wv[gi].z, c1.z, a1);
        a2 = fmaf(wv[gi].z, c2.z, a2); a3 = fmaf(wv[gi].z, c3.z, a3);
        a0 = fmaf(wv[gi].w, c0.w, a0); a1 = fmaf(wv[gi].w, c1.w, a1);
        a2 = fmaf(wv[gi].w, c2.w, a2); a3 = fmaf(wv[gi].w, c3.w, a3);
        acc[gi][0] = a0; acc[gi][1] = a1; acc[gi][2] = a2; acc[gi][3] = a3;
      }
    }
    if (kt < 7){                               // write-late into other buffer
#pragma unroll
      for (int j = 0; j < 6; ++j){
        const int qid = j*128 + tid, row = qid >> 3, q = qid & 7;
        *(float4*)&wl[buf^1][row*36 + q*4] = wreg[j];
      }
#pragma unroll
      for (int j = 0; j < 4; ++j){
        const int qid = j*128 + tid, row = qid >> 3, q = qid & 7;
        *(float4*)&cl[buf^1][row*36 + q*4] = creg[j];
      }
    }
    __syncthreads();
  }
  // partial output [t][96]
  float* o = (s == 0) ? (P0 + n*16384)
           : (s == 1) ? (P1 + n*16384)
                      : (P2 + n*8192);
#pragma unroll
  for (int r = 0; r < 4; ++r){
    const int t = ta*4 + r;
#pragma unroll
    for (int q = 0; q < 3; ++q)
      *(float4*)&o[t*96 + b*12 + q*4] =
          make_float4(acc[4*q][r], acc[4*q+1][r], acc[4*q+2][r], acc[4*q+3][r]);
  }
}

// ---- k6: 2-layer GRU, wave-pipelined. block 128 = wave0 (layer0) + wave1
// (layer1, one step behind). Handoff via double-buffered 32-float LDS slots.
__global__ __launch_bounds__(128) void k6_gru(const float* __restrict__ G0,
                                              const float* __restrict__ G1,
                                              const float* __restrict__ G2,
                                              const float* __restrict__ Hpre,
                                              const float* __restrict__ Whh0,
                                              const float* __restrict__ bih0,
                                              const float* __restrict__ bhh0,
                                              const float* __restrict__ Wih1,
                                              const float* __restrict__ Whh1,
                                              const float* __restrict__ bih1,
                                              const float* __restrict__ bhh1,
                                              const float* __restrict__ fc1w,
                                              const float* __restrict__ fc1b,
                                              const float* __restrict__ fc2w,
                                              const float* __restrict__ fc2b,
                                              const float* __restrict__ fc3w,
                                              const float* __restrict__ fc3b,
                                              float* __restrict__ ct,
                                              float* __restrict__ dout){
  const int n = blockIdx.x, tid = threadIdx.x;
  const int wid = tid >> 6, l = tid & 63;
  const int g2 = l & 31, co = (l >> 5) * 16;
  __shared__ float ginS[6144];                 // 24 KB summed gate inputs [t][96]
  __shared__ float h0buf[2][32];
  __shared__ float h1buf[2][32];
  __shared__ float hist[64][33];
  __shared__ float Wst[32][33];
  __shared__ float b1s[32], b2s[32], w3s[32];
  // ---- stage gin = G0+G1+G2 (128 threads, 12 float4 each) ----
  {
    const float4* p0 = (const float4*)(G0 + n*16384);
    const float4* p1 = (const float4*)(G1 + n*16384);
    const float4* p2 = (const float4*)(G2 + n*8192);
    float4* gs = (float4*)ginS;
#pragma unroll
    for (int j = 0; j < 12; ++j){
      int idx = j*128 + tid;
      float4 a = p0[idx], b = p1[idx], c = p2[idx];
      gs[idx] = make_float4(a.x+b.x+c.x, a.y+b.y+c.y, a.z+b.z+c.z, a.w+b.w+c.w);
    }
  }
  // ---- FC-head staging ----
  if (tid < 32){
    b1s[tid] = fc1b[n*32 + tid];
    b2s[tid] = fc2b[n*32 + tid];
    w3s[tid] = fc3w[n*32 + tid];
  }
  for (int idx = tid; idx < 1024; idx += 128) Wst[idx>>5][idx&31] = fc1w[n*1024 + idx];
  // ---- per-wave weights (wave0: Whh0; wave1: Wih1 + Whh1) ----
  float wr_[16], wz_[16], wn_[16];
  float ur_[16], uz_[16], un_[16];
  {
    const float* WA = (wid == 0) ? (Whh0 + n*3072) : (Wih1 + n*3072);
#pragma unroll
    for (int q = 0; q < 4; ++q){
      float4 v;
      v = *(const float4*)(WA + g2*32 + co + 4*q);       wr_[4*q]=v.x; wr_[4*q+1]=v.y; wr_[4*q+2]=v.z; wr_[4*q+3]=v.w;
      v = *(const float4*)(WA + (32+g2)*32 + co + 4*q);  wz_[4*q]=v.x; wz_[4*q+1]=v.y; wz_[4*q+2]=v.z; wz_[4*q+3]=v.w;
      v = *(const float4*)(WA + (64+g2)*32 + co + 4*q);  wn_[4*q]=v.x; wn_[4*q+1]=v.y; wn_[4*q+2]=v.z; wn_[4*q+3]=v.w;
    }
    if (wid == 1){
      const float* WB = Whh1 + n*3072;
#pragma unroll
      for (int q = 0; q < 4; ++q){
        float4 v;
        v = *(const float4*)(WB + g2*32 + co + 4*q);       ur_[4*q]=v.x; ur_[4*q+1]=v.y; ur_[4*q+2]=v.z; ur_[4*q+3]=v.w;
        v = *(const float4*)(WB + (32+g2)*32 + co + 4*q);  uz_[4*q]=v.x; uz_[4*q+1]=v.y; uz_[4*q+2]=v.z; uz_[4*q+3]=v.w;
        v = *(const float4*)(WB + (64+g2)*32 + co + 4*q);  un_[4*q]=v.x; un_[4*q+1]=v.y; un_[4*q+2]=v.z; un_[4*q+3]=v.w;
      }
    }
  }
  const float* bip = (wid == 0) ? bih0 : bih1;
  const float* bhp = (wid == 0) ? bhh0 : bhh1;
  const float br = bip[n*96 + g2], bz = bip[n*96 + 32 + g2], bn = bip[n*96 + 64 + g2];
  const float cr = bhp[n*96 + g2], cz = bhp[n*96 + 32 + g2], cn = bhp[n*96 + 64 + g2];
  // ---- initial state ----
  const float* hp = (wid == 0) ? (Hpre + n*32) : (Hpre + 8192 + n*32);
  float hown = hp[g2];
  float hs[16];
#pragma unroll
  for (int q = 0; q < 4; ++q){
    float4 v = *(const float4*)&hp[co + 4*q];
    hs[4*q]=v.x; hs[4*q+1]=v.y; hs[4*q+2]=v.z; hs[4*q+3]=v.w;
  }
  // ---- pipelined slot loop: wave0 computes h0(s) for s<64; wave1 h1(s-1) ----
  for (int s = 0; s < 65; ++s){
    __syncthreads();
    if (wid == 0){
      if (s < 64){
        const float gr = ginS[s*96 + g2], gz = ginS[s*96 + 32 + g2], gn = ginS[s*96 + 64 + g2];
        if (s > 0){
#pragma unroll
          for (int q = 0; q < 4; ++q){
            float4 v = *(const float4*)&h0buf[(s-1)&1][co + 4*q];
            hs[4*q]=v.x; hs[4*q+1]=v.y; hs[4*q+2]=v.z; hs[4*q+3]=v.w;
          }
        }
        float pr = 0.f, pz = 0.f, pn = 0.f;
#pragma unroll
        for (int j = 0; j < 16; ++j){
          pr = fmaf(wr_[j], hs[j], pr);
          pz = fmaf(wz_[j], hs[j], pz);
          pn = fmaf(wn_[j], hs[j], pn);
        }
        pr += __shfl_xor(pr, 32);
        pz += __shfl_xor(pz, 32);
        pn += __shfl_xor(pn, 32);
        const float r = sigf(gr + br + pr + cr);
        const float z = sigf(gz + bz + pz + cz);
        const float nn = tanhfa(gn + bn + r*(pn + cn));
        hown = (1.f - z)*nn + z*hown;
        if (l < 32) h0buf[s & 1][g2] = hown;
      }
    } else {
      if (s >= 1){
        const int t = s - 1;
        if (s > 1){
#pragma unroll
          for (int q = 0; q < 4; ++q){
            float4 v = *(const float4*)&h1buf[(s-1)&1][co + 4*q];
            hs[4*q]=v.x; hs[4*q+1]=v.y; hs[4*q+2]=v.z; hs[4*q+3]=v.w;
          }
        }
        float hx[16];
#pragma unroll
        for (int q = 0; q < 4; ++q){
          float4 v = *(const float4*)&h0buf[(s-1)&1][co + 4*q];
          hx[4*q]=v.x; hx[4*q+1]=v.y; hx[4*q+2]=v.z; hx[4*q+3]=v.w;
        }
        float qr = 0.f, qz = 0.f, qn = 0.f, sr = 0.f, sz = 0.f, sn = 0.f;
#pragma unroll
        for (int j = 0; j < 16; ++j){
          qr = fmaf(wr_[j], hx[j], qr);  sr = fmaf(ur_[j], hs[j], sr);
          qz = fmaf(wz_[j], hx[j], qz);  sz = fmaf(uz_[j], hs[j], sz);
          qn = fmaf(wn_[j], hx[j], qn);  sn = fmaf(un_[j], hs[j], sn);
        }
        float vr = qr + sr; vr += __shfl_xor(vr, 32);
        float vz = qz + sz; vz += __shfl_xor(vz, 32);
        qn += __shfl_xor(qn, 32);
        sn += __shfl_xor(sn, 32);
        const float r1 = sigf(vr + br + cr);
        const float z1 = sigf(vz + bz + cz);
        const float n1 = tanhfa(qn + bn + r1*(sn + cn));
        hown = (1.f - z1)*n1 + z1*hown;
        if (l < 32){ h1buf[s & 1][g2] = hown; hist[t][g2] = hown; }
      }
    }
  }
  if (wid == 0 && l < 32) dout[16384 + n*32 + g2] = hown;
  if (wid == 1 && l < 32) dout[16384 + 8192 + n*32 + g2] = hown;
  __syncthreads();
  // ---- fused FC head on first 64 threads (sensor = tid) ----
  float r1a[32];
  if (tid < 64){
    float hr[32];
#pragma unroll
    for (int k = 0; k < 32; ++k) hr[k] = hist[tid][k];
#pragma unroll
    for (int k = 0; k < 32; ++k){
      float a0=0.f,a1=0.f,a2=0.f,a3=0.f;
#pragma unroll
      for (int q = 0; q < 32; q += 4){
        a0 = fmaf(hr[q],   Wst[k][q],   a0);
        a1 = fmaf(hr[q+1], Wst[k][q+1], a1);
        a2 = fmaf(hr[q+2], Wst[k][q+2], a2);
        a3 = fmaf(hr[q+3], Wst[k][q+3], a3);
      }
      float v = b1s[k] + ((a0+a1)+(a2+a3));
      r1a[k] = v > 0.f ? v : 0.f;
    }
  }
  __syncthreads();
  for (int idx = tid; idx < 1024; idx += 128) Wst[idx>>5][idx&31] = fc2w[n*1024 + idx];
  __syncthreads();
  if (tid < 64){
    float r2a[32];
#pragma unroll
    for (int k = 0; k < 32; ++k){
      float a0=0.f,a1=0.f,a2=0.f,a3=0.f;
#pragma unroll
      for (int q = 0; q < 32; q += 4){
        a0 = fmaf(r1a[q],   Wst[k][q],   a0);
        a1 = fmaf(r1a[q+1], Wst[k][q+1], a1);
        a2 = fmaf(r1a[q+2], Wst[k][q+2], a2);
        a3 = fmaf(r1a[q+3], Wst[k][q+3], a3);
      }
      float v = b2s[k] + ((a0+a1)+(a2+a3));
      r2a[k] = v > 0.f ? v : 0.f;
    }
    float v = fc3b[n];
#pragma unroll
    for (int k = 0; k < 32; ++k) v = fmaf(r2a[k], w3s[k], v);
    ct[n*64 + tid] = v;
  }
}

// ---- k8a: Wh (transposed) + f1/f2 for out & out1. grid 8 = gat*4 + row-quarter ----
__global__ __launch_bounds__(256) void k8a(const float* __restrict__ ct,
                                           const float* __restrict__ W0,
                                           const float* __restrict__ a0,
                                           const float* __restrict__ W1,
                                           const float* __restrict__ a1,
                                           float* __restrict__ WhABt,
                                           float* __restrict__ OF1,
                                           float* __restrict__ OF2){
  const int gat = blockIdx.x >> 2, rq = blockIdx.x & 3, r0 = rq*64;
  const int tid = threadIdx.x;
  const int ii = tid & 63, cq = tid >> 6;
  __shared__ float ctl[64][65];
  __shared__ float Wl[64][68];
  __shared__ float a1s[64], a2s[64];
  __shared__ float red[64][4][2];
  const float* W = gat ? W1 : W0;
  const float* aa = gat ? a1 : a0;
  for (int idx = tid; idx < 4096; idx += 256){
    int i2 = idx >> 6, k = idx & 63;
    ctl[i2][k] = ct[(r0 + i2)*64 + k];
  }
  for (int idx = tid; idx < 4096; idx += 256){
    int k = idx >> 6, c = idx & 63;
    Wl[k][c] = W[k*64 + c];
  }
  if (tid < 64){ a1s[tid] = aa[tid]; a2s[tid] = aa[64 + tid]; }
  __syncthreads();
  float acc[16];
#pragma unroll
  for (int c = 0; c < 16; ++c) acc[c] = 0.f;
#pragma unroll 2
  for (int k = 0; k < 64; ++k){
    float v = ctl[ii][k];
    const float* wr = &Wl[k][cq*16];
#pragma unroll
    for (int c = 0; c < 16; ++c) acc[c] = fmaf(v, wr[c], acc[c]);
  }
  float p1 = 0.f, p2 = 0.f;
#pragma unroll
  for (int c = 0; c < 16; ++c){
    p1 = fmaf(acc[c], a1s[cq*16 + c], p1);
    p2 = fmaf(acc[c], a2s[cq*16 + c], p2);
  }
  red[ii][cq][0] = p1; red[ii][cq][1] = p2;
  float* o = WhABt + gat*16384;
#pragma unroll
  for (int c = 0; c < 16; ++c) o[(cq*16 + c)*256 + r0 + ii] = acc[c];
  __syncthreads();
  if (cq == 0){
    OF1[gat*256 + r0 + ii] = red[ii][0][0] + red[ii][1][0] + red[ii][2][0] + red[ii][3][0];
    OF2[gat*256 + r0 + ii] = red[ii][0][1] + red[ii][1][1] + red[ii][2][1] + red[ii][3][1];
  }
}

// ---- k8b: out/out1 attention, single-pass online softmax. grid 8 ----
__global__ __launch_bounds__(256) void k8b(const float* __restrict__ WhABt,
                                           const float* __restrict__ OF1,
                                           const float* __restrict__ OF2,
                                           const unsigned* __restrict__ maskA,
                                           float* __restrict__ OUTT){
  const int gat = blockIdx.x >> 2, c0 = (blockIdx.x & 3) * 16;
  const int i = threadIdx.x;
  __shared__ float wt[4096];                   // [16 c][256 j]
  __shared__ float f2s[256];
  __shared__ float wmax[4];
  {
    const int w = i >> 6, l = i & 63;
    const float* src = WhABt + gat*16384 + c0*256 + w*1024 + l*4;
    float* dst = &wt[w*1024];
#pragma unroll
    for (int r = 0; r < 4; ++r) gl2lds16(src + r*256, dst + r*256);
  }
  const float f1  = OF1[gat*256 + i];
  const float f2v = OF2[gat*256 + i];
  f2s[i] = f2v;
  unsigned mw[8];
#pragma unroll
  for (int w = 0; w < 8; ++w) mw[w] = maskA[i*8 + w];
  float wm = f2v;
#pragma unroll
  for (int d = 1; d < 64; d <<= 1) wm = fmaxf(wm, __shfl_xor(wm, d));
  if ((i & 63) == 0) wmax[i >> 6] = wm;
  asm volatile("s_waitcnt vmcnt(0)" ::: "memory");
  __syncthreads();
  const float mb = fmaxf(fmaxf(wmax[0], wmax[1]), fmaxf(wmax[2], wmax[3]));
  const float tm = f1 + mb;
  const float m  = (tm > 0.f) ? tm : ALPHA*tm;
  float acc[16];
#pragma unroll
  for (int c = 0; c < 16; ++c) acc[c] = 0.f;
  float s = 0.f;
#pragma unroll 2
  for (int jb = 0; jb < 64; ++jb){
    const float4 f2q = *(const float4*)&f2s[jb*4];
    const unsigned mk = mw[jb >> 3];
    const int sh = (jb & 7) * 4;
    float t0 = f1 + f2q.x; t0 = (t0 > 0.f) ? t0 : ALPHA*t0;
    float t1 = f1 + f2q.y; t1 = (t1 > 0.f) ? t1 : ALPHA*t1;
    float t2 = f1 + f2q.z; t2 = (t2 > 0.f) ? t2 : ALPHA*t2;
    float t3 = f1 + f2q.w; t3 = (t3 > 0.f) ? t3 : ALPHA*t3;
    const float e0 = ((mk >> (sh+0)) & 1u) ? __expf(t0 - m) : 0.f;
    const float e1 = ((mk >> (sh+1)) & 1u) ? __expf(t1 - m) : 0.f;
    const float e2 = ((mk >> (sh+2)) & 1u) ? __expf(t2 - m) : 0.f;
    const float e3 = ((mk >> (sh+3)) & 1u) ? __expf(t3 - m) : 0.f;
    s += (e0 + e1) + (e2 + e3);
#pragma unroll
    for (int c = 0; c < 16; ++c){
      const float4 wv = *(const float4*)&wt[c*256 + jb*4];
      acc[c] = fmaf(e0, wv.x, fmaf(e1, wv.y, fmaf(e2, wv.z, fmaf(e3, wv.w, acc[c]))));
    }
  }
  const float inv = (s > 0.f) ? __builtin_amdgcn_rcpf(s) : 0.f;
#pragma unroll
  for (int c = 0; c < 16; ++c) OUTT[gat*16384 + (c0+c)*256 + i] = acc[c] * inv;
}

// ---- k8c: Wh2 (transposed) + F1B/F2B. grid 8 = 32-row chunks ----
__global__ __launch_bounds__(256) void k8c(const float* __restrict__ OUTT,
                                           const float* __restrict__ W2,
                                           const float* __restrict__ a2,
                                           float* __restrict__ Wh2,
                                           float* __restrict__ F1B,
                                           float* __restrict__ F2B){
  const int r0 = blockIdx.x * 32;
  const int tid = threadIdx.x;
  const int ii = tid & 31, cq = tid >> 5;      // 8 groups x 8 cols
  __shared__ float W2l[128][68];
  __shared__ float a1s[64], a2s[64];
  __shared__ float red[32][8][2];
  for (int idx = tid; idx < 8192; idx += 256){
    int k = idx >> 6, c = idx & 63;
    W2l[k][c] = W2[k*64 + c];
  }
  if (tid < 64){ a1s[tid] = a2[tid]; a2s[tid] = a2[64 + tid]; }
  __syncthreads();
  float acc[8];
#pragma unroll
  for (int c = 0; c < 8; ++c) acc[c] = 0.f;
#pragma unroll 2
  for (int k = 0; k < 128; ++k){
    float v = OUTT[(k >> 6)*16384 + (k & 63)*256 + r0 + ii];
    const float* wr = &W2l[k][cq*8];
#pragma unroll
    for (int c = 0; c < 8; ++c) acc[c] = fmaf(v, wr[c], acc[c]);
  }
  float p1 = 0.f, p2 = 0.f;
#pragma unroll
  for (int c = 0; c < 8; ++c){
    p1 = fmaf(acc[c], a1s[cq*8 + c], p1);
    p2 = fmaf(acc[c], a2s[cq*8 + c], p2);
  }
  red[ii][cq][0] = p1; red[ii][cq][1] = p2;
#pragma unroll
  for (int c = 0; c < 8; ++c) Wh2[(cq*8 + c)*256 + r0 + ii] = acc[c];
  __syncthreads();
  if (cq == 0){
    float s1 = 0.f, s2 = 0.f;
#pragma unroll
    for (int q = 0; q < 8; ++q){ s1 += red[ii][q][0]; s2 += red[ii][q][1]; }
    F1B[r0 + ii] = s1; F2B[r0 + ii] = s2;
  }
}

// ---- k8d: final GAT -> d_out, single-pass online softmax. grid 4 ----
__global__ __launch_bounds__(256) void k8d(const float* __restrict__ Wh2,
                                           const float* __restrict__ F1B,
                                           const float* __restrict__ F2B,
                                           const unsigned* __restrict__ maskA,
                                           float* __restrict__ dOut){
  const int c0 = blockIdx.x * 16;
  const int i = threadIdx.x;
  __shared__ float wt[4096];                   // [16 c][256 j]
  __shared__ float f2s[256];
  __shared__ float wmax[4];
  {
    const int w = i >> 6, l = i & 63;
    const float* src = Wh2 + c0*256 + w*1024 + l*4;
    float* dst = &wt[w*1024];
#pragma unroll
    for (int r = 0; r < 4; ++r) gl2lds16(src + r*256, dst + r*256);
  }
  const float f1  = F1B[i];
  const float f2v = F2B[i];
  f2s[i] = f2v;
  unsigned mw[8];
#pragma unroll
  for (int w = 0; w < 8; ++w) mw[w] = maskA[i*8 + w];
  float wm = f2v;
#pragma unroll
  for (int d = 1; d < 64; d <<= 1) wm = fmaxf(wm, __shfl_xor(wm, d));
  if ((i & 63) == 0) wmax[i >> 6] = wm;
  asm volatile("s_waitcnt vmcnt(0)" ::: "memory");
  __syncthreads();
  const float mb = fmaxf(fmaxf(wmax[0], wmax[1]), fmaxf(wmax[2], wmax[3]));
  const float tm = f1 + mb;
  const float m  = (tm > 0.f) ? tm : ALPHA*tm;
  float acc[16];
#pragma unroll
  for (int c = 0; c < 16; ++c) acc[c] = 0.f;
  float s = 0.f;
#pragma unroll 2
  for (int jb = 0; jb < 64; ++jb){
    const float4 f2q = *(const float4*)&f2s[jb*4];
    const unsigned mk = mw[jb >> 3];
    const int sh = (jb & 7) * 4;
    float t0 = f1 + f2q.x; t0 = (t0 > 0.f) ? t0 : ALPHA*t0;
    float t1 = f1 + f2q.y; t1 = (t1 > 0.f) ? t1 : ALPHA*t1;
    float t2 = f1 + f2q.z; t2 = (t2 > 0.f) ? t2 : ALPHA*t2;
    float t3 = f1 + f2q.w; t3 = (t3 > 0.f) ? t3 : ALPHA*t3;
    const float e0 = ((mk >> (sh+0)) & 1u) ? __expf(t0 - m) : 0.f;
    const float e1 = ((mk >> (sh+1)) & 1u) ? __expf(t1 - m) : 0.f;
    const float e2 = ((mk >> (sh+2)) & 1u) ? __expf(t2 - m) : 0.f;
    const float e3 = ((mk >> (sh+3)) & 1u) ? __expf(t3 - m) : 0.f;
    s += (e0 + e1) + (e2 + e3);
#pragma unroll
    for (int c = 0; c < 16; ++c){
      const float4 wv = *(const float4*)&wt[c*256 + jb*4];
      acc[c] = fmaf(e0, wv.x, fmaf(e1, wv.y, fmaf(e2, wv.z, fmaf(e3, wv.w, acc[c]))));
    }
  }
  const float inv = (s > 0.f) ? __builtin_amdgcn_rcpf(s) : 0.f;
#pragma unroll
  for (int c = 0; c < 16; ++c) dOut[i*64 + c0 + c] = acc[c] * inv;
}

extern "C" void kernel_launch(void* const* d_in, const int* in_sizes, int n_in,
                              void* d_out, int out_size, void* d_ws, size_t ws_size,
                              hipStream_t stream){
  (void)in_sizes; (void)n_in; (void)out_size; (void)ws_size;
  const float* x     = (const float*)d_in[0];
  const float* Fadj  = (const float*)d_in[1];
  const float* Tadj  = (const float*)d_in[2];
  const float* adj   = (const float*)d_in[3];
  const float* Hpre  = (const float*)d_in[4];
  const float* FattW = (const float*)d_in[5];
  const float* Fatta = (const float*)d_in[6];
  const float* TattW = (const float*)d_in[7];
  const float* Tatta = (const float*)d_in[8];
  const float* Wih0  = (const float*)d_in[9];
  const float* Whh0  = (const float*)d_in[10];
  const float* bih0  = (const float*)d_in[11];
  const float* bhh0  = (const float*)d_in[12];
  const float* Wih1  = (const float*)d_in[13];
  const float* Whh1  = (const float*)d_in[14];
  const float* bih1  = (const float*)d_in[15];
  const float* bhh1  = (const float*)d_in[16];
  const float* fc1w  = (const float*)d_in[17];
  const float* fc1b  = (const float*)d_in[18];
  const float* fc2w  = (const float*)d_in[19];
  const float* fc2b  = (const float*)d_in[20];
  const float* fc3w  = (const float*)d_in[21];
  const float* fc3b  = (const float*)d_in[22];
  const float* oW    = (const float*)d_in[23];
  const float* oa    = (const float*)d_in[24];
  const float* o1W   = (const float*)d_in[25];
  const float* o1a   = (const float*)d_in[26];
  const float* o2W   = (const float*)d_in[27];
  const float* o2a   = (const float*)d_in[28];
  float* out = (float*)d_out;

  float* ws = (float*)d_ws;
  float* R0 = ws;
  float* R1 = ws + 4194304;
  float* R2 = ws + 8388608;
  unsigned* maskT = (unsigned*)R2;             // 524288 words
  float* Tf1p = R2 + 524288;                   // 2 x 65536
  float* Tf2p = R2 + 655360;                   // 2 x 65536
  unsigned* maskA = (unsigned*)(ws + 12582912);// 2048 words
  float* WhTt = R0;
  float* WhF  = R0;
  float* TatT = R1;
  float* Fat  = R2;
  float* P0 = R2;
  float* P1 = R1;
  float* P2 = R0;
  float* ctb   = R0 + 2097152;                 // above P2's span
  float* WhABt = R1 + 16384;
  float* OF1   = R1 + 49152;
  float* OF2   = R1 + 49664;
  float* OUTT  = R1 + 50176;
  float* WH2   = R1 + 82944;
  float* F1B   = R1 + 99328;
  float* F2B   = R1 + 99584;

  k_mask<<<1024, 256, 0, stream>>>(Tadj, maskT, 16777216);
  k_mask<<<32, 256, 0, stream>>>(adj, maskA, 65536);
  k3_wht<<<512, 256, 0, stream>>>(x, TattW, Tatta, WhTt, Tf1p, Tf2p);
  k4_tat<<<512, 256, 0, stream>>>(WhTt, Tf1p, Tf2p, maskT, TatT);
  k1_whf<<<512, 256, 0, stream>>>(x, FattW, WhF);
  k2_fat<<<256, 512, 0, stream>>>(WhF, Fatta, Fadj, Fat);
  k5_gi0<<<768, 128, 0, stream>>>(Fat, TatT, x, Wih0, P0, P1, P2);
  k6_gru<<<256, 128, 0, stream>>>(P0, P1, P2, Hpre, Whh0, bih0, bhh0, Wih1, Whh1, bih1, bhh1,
                                  fc1w, fc1b, fc2w, fc2b, fc3w, fc3b, ctb, out);
  k8a<<<8, 256, 0, stream>>>(ctb, oW, oa, o1W, o1a, WhABt, OF1, OF2);
  k8b<<<8, 256, 0, stream>>>(WhABt, OF1, OF2, maskA, OUTT);
  k8c<<<8, 256, 0, stream>>>(OUTT, o2W, o2a, WH2, F1B, F2B);
  k8d<<<4, 256, 0, stream>>>(WH2, F1B, F2B, maskA, out);
}

// Round 9
// 585.444 us; speedup vs baseline: 1.3319x; 1.3319x over previous
//
#include <hip/hip_runtime.h>
#include <hip/hip_bf16.h>

__device__ __forceinline__ float sigf(float x){ return __builtin_amdgcn_rcpf(1.f+__expf(-x)); }
__device__ __forceinline__ float tanhfa(float x){
  return 1.f - 2.f*__builtin_amdgcn_rcpf(1.f + __expf(2.f*x));
}

#define ALPHA 0.2f
#define NEGV  -9e15f

// N=256 nodes, S=64 sensors, W=256 window, H=32 hidden. All fp32.

__device__ __forceinline__ void gl2lds16(const float* g, float* l){
  __builtin_amdgcn_global_load_lds(
      (const __attribute__((address_space(1))) void*)g,
      (__attribute__((address_space(3))) void*)l, 16, 0, 0);
}

// ---- k_mask: pack adjacency fp32 (0/1) -> bitmask via wave ballot ----
__global__ __launch_bounds__(256) void k_mask(const float* __restrict__ src,
                                              unsigned* __restrict__ dst, int nelem){
  const int stride = gridDim.x * blockDim.x;
  const int lane = threadIdx.x & 63;
  for (int e = blockIdx.x*blockDim.x + threadIdx.x; e < nelem; e += stride){
    unsigned long long m = __ballot(src[e] > 0.f);
    if (lane == 0)       dst[e >> 5] = (unsigned)m;
    else if (lane == 32) dst[e >> 5] = (unsigned)(m >> 32);
  }
}

// ---- k3: Wh_T + Tf1/Tf2 partials. grid 512 = n*2 + c-half ----
// WhTt stored i-major: WhTt[n][i][64 c] (k4 stages [j][c] tiles linearly).
__global__ __launch_bounds__(256) void k3_wht(const float* __restrict__ x,
                                              const float* __restrict__ TW,
                                              const float* __restrict__ Ta,
                                              float* __restrict__ WhTt,
                                              float* __restrict__ Tf1p,
                                              float* __restrict__ Tf2p){
  const int n = blockIdx.x >> 1, ch = blockIdx.x & 1, c0 = ch*32;
  const int tid = threadIdx.x;
  __shared__ float Wm[64][36];
  __shared__ float as1[32], as2[32];
  for (int idx = tid; idx < 2048; idx += 256){
    int k = idx >> 5, cc = idx & 31;
    Wm[k][cc] = TW[n*4096 + k*64 + c0 + cc];
  }
  if (tid < 32){ as1[tid] = Ta[n*128 + c0 + tid]; as2[tid] = Ta[n*128 + 64 + c0 + tid]; }
  __syncthreads();
  const int i = tid;
  const float* xn = x + n*16384;
  float acc[32];
#pragma unroll
  for (int c = 0; c < 32; ++c) acc[c] = 0.f;
#pragma unroll 2
  for (int k = 0; k < 64; ++k){
    float xv = xn[k*256 + i];                  // coalesced
    const float* wr = &Wm[k][0];               // broadcast b128
#pragma unroll
    for (int c = 0; c < 32; ++c) acc[c] = fmaf(xv, wr[c], acc[c]);
  }
  float f1 = 0.f, f2 = 0.f;
#pragma unroll
  for (int c = 0; c < 32; ++c){ f1 = fmaf(acc[c], as1[c], f1); f2 = fmaf(acc[c], as2[c], f2); }
  Tf1p[ch*65536 + n*256 + i] = f1;
  Tf2p[ch*65536 + n*256 + i] = f2;
  float* o = WhTt + n*16384 + i*64 + c0;       // i-major store
#pragma unroll
  for (int q = 0; q < 8; ++q)
    *(float4*)&o[4*q] = make_float4(acc[4*q], acc[4*q+1], acc[4*q+2], acc[4*q+3]);
}

// ---- k4: time-GAT attention, two-phase register-tiled PV. grid 512 = n*2+ch ----
__global__ __launch_bounds__(256) void k4_tat(const float* __restrict__ WhTt,
                                              const float* __restrict__ Tf1p,
                                              const float* __restrict__ Tf2p,
                                              const unsigned* __restrict__ maskT,
                                              float* __restrict__ TatT){
  const int n = blockIdx.x >> 1, ch = blockIdx.x & 1, c0 = ch*32;
  const int tid = threadIdx.x;
  __shared__ float wtL[8192];                  // [256 j][32 c], 32 KB
  __shared__ float ptb[8192];                  // [32 jj][256 i], 32 KB
  __shared__ float f2s[256];
  __shared__ float ssum[256];
  __shared__ float wmax[4];
  {                                            // stage wt: lane = (row l>>3, quad l&7)
    const int w = tid >> 6, l = tid & 63;
    const float* src = WhTt + n*16384 + (w*64 + (l>>3))*64 + c0 + (l&7)*4;
    float* dst = &wtL[w*2048];
#pragma unroll
    for (int r = 0; r < 8; ++r) gl2lds16(src + r*512, dst + r*256);
  }
  const float f1  = Tf1p[n*256 + tid] + Tf1p[65536 + n*256 + tid];
  const float f2v = Tf2p[n*256 + tid] + Tf2p[65536 + n*256 + tid];
  f2s[tid] = f2v;
  unsigned mw[8];
#pragma unroll
  for (int w = 0; w < 8; ++w) mw[w] = maskT[n*2048 + tid*8 + w];
  float wm = f2v;
#pragma unroll
  for (int d = 1; d < 64; d <<= 1) wm = fmaxf(wm, __shfl_xor(wm, d));
  if ((tid & 63) == 0) wmax[tid >> 6] = wm;
  asm volatile("s_waitcnt vmcnt(0)" ::: "memory");
  __syncthreads();
  const float mb = fmaxf(fmaxf(wmax[0], wmax[1]), fmaxf(wmax[2], wmax[3]));
  const float tm = f1 + mb;
  const float m  = (tm > 0.f) ? tm : ALPHA*tm;
  const int iq = tid & 63, cq = tid >> 6;
  float acc[4][8];
#pragma unroll
  for (int r = 0; r < 4; ++r)
#pragma unroll
    for (int c = 0; c < 8; ++c) acc[r][c] = 0.f;
  float sloc = 0.f;
  for (int jt = 0; jt < 8; ++jt){
    const int j0 = jt*32;
    // ---- phase A: P-tile row tid ----
#pragma unroll
    for (int jj = 0; jj < 32; jj += 4){
      const float4 f2q = *(const float4*)&f2s[j0 + jj];
      const unsigned mk = mw[(j0 + jj) >> 5];
      const int sh = (j0 + jj) & 31;
      float t0 = f1 + f2q.x; t0 = (t0 > 0.f) ? t0 : ALPHA*t0;
      float t1 = f1 + f2q.y; t1 = (t1 > 0.f) ? t1 : ALPHA*t1;
      float t2 = f1 + f2q.z; t2 = (t2 > 0.f) ? t2 : ALPHA*t2;
      float t3 = f1 + f2q.w; t3 = (t3 > 0.f) ? t3 : ALPHA*t3;
      const float e0 = ((mk >> (sh+0)) & 1u) ? __expf(t0 - m) : 0.f;
      const float e1 = ((mk >> (sh+1)) & 1u) ? __expf(t1 - m) : 0.f;
      const float e2 = ((mk >> (sh+2)) & 1u) ? __expf(t2 - m) : 0.f;
      const float e3 = ((mk >> (sh+3)) & 1u) ? __expf(t3 - m) : 0.f;
      sloc += (e0 + e1) + (e2 + e3);
      ptb[(jj+0)*256 + tid] = e0;
      ptb[(jj+1)*256 + tid] = e1;
      ptb[(jj+2)*256 + tid] = e2;
      ptb[(jj+3)*256 + tid] = e3;
    }
    __syncthreads();
    // ---- phase B: acc[4 rows][8 c] ----
#pragma unroll 4
    for (int jj = 0; jj < 32; ++jj){
      const float4 p4 = *(const float4*)&ptb[jj*256 + 4*iq];      // distinct lanes
      const float4 w0 = *(const float4*)&wtL[(j0+jj)*32 + cq*8];  // broadcast
      const float4 w1 = *(const float4*)&wtL[(j0+jj)*32 + cq*8 + 4];
#pragma unroll
      for (int r = 0; r < 4; ++r){
        const float pv = (r == 0) ? p4.x : (r == 1) ? p4.y : (r == 2) ? p4.z : p4.w;
        acc[r][0] = fmaf(pv, w0.x, acc[r][0]);
        acc[r][1] = fmaf(pv, w0.y, acc[r][1]);
        acc[r][2] = fmaf(pv, w0.z, acc[r][2]);
        acc[r][3] = fmaf(pv, w0.w, acc[r][3]);
        acc[r][4] = fmaf(pv, w1.x, acc[r][4]);
        acc[r][5] = fmaf(pv, w1.y, acc[r][5]);
        acc[r][6] = fmaf(pv, w1.z, acc[r][6]);
        acc[r][7] = fmaf(pv, w1.w, acc[r][7]);
      }
    }
    __syncthreads();
  }
  ssum[tid] = sloc;
  __syncthreads();
  float* o = TatT + n*16384;
#pragma unroll
  for (int r = 0; r < 4; ++r){
    const int i2 = 4*iq + r;
    const float sv = ssum[i2];
    const float inv = (sv > 0.f) ? __builtin_amdgcn_rcpf(sv) : 0.f;
#pragma unroll
    for (int cc = 0; cc < 8; ++cc)
      o[(c0 + cq*8 + cc)*256 + i2] = acc[r][cc] * inv;
  }
}

// ---- k1: Wh_F = x @ Fatt_W. grid 512 = n*2 + c-half(128), block 256 ----
__global__ __launch_bounds__(256) void k1_whf(const float* __restrict__ x,
                                              const float* __restrict__ FW,
                                              float* __restrict__ WhF){
  const int n = blockIdx.x >> 1, ch = blockIdx.x & 1, c0 = ch*128;
  const int tid = threadIdx.x;
  __shared__ float xt[16384];                  // [i][k] linear, 64 KB
  {
    const int w = tid >> 6, l = tid & 63;
    const float* xg = x + n*16384 + w*4096 + l*4;
    float* ld = &xt[w*4096];
#pragma unroll
    for (int j = 0; j < 16; ++j) gl2lds16(xg + j*256, ld + j*256);
  }
  asm volatile("s_waitcnt vmcnt(0)" ::: "memory");
  __syncthreads();
  const int cq = tid & 31, iq = tid >> 5;      // c-quad, i-group(8 rows)
  const int cc = c0 + cq*4;
  const float* Wn = FW + (size_t)n*65536 + cc;
  const float* xrow = &xt[iq*8*256];
  float acc[8][4];
#pragma unroll
  for (int i = 0; i < 8; ++i)
#pragma unroll
    for (int c = 0; c < 4; ++c) acc[i][c] = 0.f;
#pragma unroll 2
  for (int k4 = 0; k4 < 64; ++k4){
    const float4 w0 = *(const float4*)&Wn[(4*k4+0)*256];
    const float4 w1 = *(const float4*)&Wn[(4*k4+1)*256];
    const float4 w2 = *(const float4*)&Wn[(4*k4+2)*256];
    const float4 w3 = *(const float4*)&Wn[(4*k4+3)*256];
#pragma unroll
    for (int i = 0; i < 8; ++i){
      const float4 xv = *(const float4*)&xrow[i*256 + 4*k4];
      acc[i][0] = fmaf(xv.x, w0.x, acc[i][0]); acc[i][0] = fmaf(xv.y, w1.x, acc[i][0]);
      acc[i][0] = fmaf(xv.z, w2.x, acc[i][0]); acc[i][0] = fmaf(xv.w, w3.x, acc[i][0]);
      acc[i][1] = fmaf(xv.x, w0.y, acc[i][1]); acc[i][1] = fmaf(xv.y, w1.y, acc[i][1]);
      acc[i][1] = fmaf(xv.z, w2.y, acc[i][1]); acc[i][1] = fmaf(xv.w, w3.y, acc[i][1]);
      acc[i][2] = fmaf(xv.x, w0.z, acc[i][2]); acc[i][2] = fmaf(xv.y, w1.z, acc[i][2]);
      acc[i][2] = fmaf(xv.z, w2.z, acc[i][2]); acc[i][2] = fmaf(xv.w, w3.z, acc[i][2]);
      acc[i][3] = fmaf(xv.x, w0.w, acc[i][3]); acc[i][3] = fmaf(xv.y, w1.w, acc[i][3]);
      acc[i][3] = fmaf(xv.z, w2.w, acc[i][3]); acc[i][3] = fmaf(xv.w, w3.w, acc[i][3]);
    }
  }
  float* o = WhF + n*16384 + cc;
#pragma unroll
  for (int i = 0; i < 8; ++i)
    *(float4*)&o[(iq*8 + i)*256] = make_float4(acc[i][0], acc[i][1], acc[i][2], acc[i][3]);
}

// ---- k2: feature-GAT softmax + Fat = att @ Wh. grid 256, block 512 (i-split) ----
__global__ __launch_bounds__(512) void k2_fat(const float* __restrict__ WhF,
                                              const float* __restrict__ Fa,
                                              const float* __restrict__ Fadj,
                                              float* __restrict__ Fat){
  const int n = blockIdx.x, tid = threadIdx.x;
  __shared__ float attT[64][68];               // attT[j][i]
  __shared__ float f1s[64], f2s[64];
  __shared__ float part[64][8][2];
  const float* Wh = WhF + n*16384;
  { // f1/f2: thread (i=tid>>3, q=tid&7) partial over 32 cols
    int i = tid >> 3, q = tid & 7;
    const float* an = Fa + n*512;
    float p1 = 0.f, p2 = 0.f;
    for (int cc = 0; cc < 32; ++cc){
      int c2 = q*32 + cc;
      float w = Wh[i*256 + c2];
      p1 = fmaf(w, an[c2], p1);
      p2 = fmaf(w, an[256 + c2], p2);
    }
    part[i][q][0] = p1; part[i][q][1] = p2;
  }
  __syncthreads();
  if (tid < 64){
    float s1 = 0.f, s2 = 0.f;
#pragma unroll
    for (int q = 0; q < 8; ++q){ s1 += part[tid][q][0]; s2 += part[tid][q][1]; }
    f1s[tid] = s1; f2s[tid] = s2;
  }
  __syncthreads();
  if (tid < 64){                               // masked softmax row -> attT column
    const int r = tid;
    const float f1 = f1s[r];
    const float* adjr = Fadj + n*4096 + r*64;
    unsigned m0 = 0, m1 = 0;
#pragma unroll
    for (int j = 0; j < 32; ++j) if (adjr[j] > 0.f) m0 |= (1u << j);
#pragma unroll
    for (int j = 0; j < 32; ++j) if (adjr[32+j] > 0.f) m1 |= (1u << j);
    float m = -INFINITY;
#pragma unroll
    for (int j = 0; j < 64; ++j){
      float e = f1 + f2s[j]; e = (e > 0.f) ? e : ALPHA*e;
      unsigned bit = (j < 32) ? ((m0 >> j) & 1u) : ((m1 >> (j-32)) & 1u);
      e = bit ? e : NEGV;
      m = fmaxf(m, e);
    }
    float s = 0.f;
#pragma unroll
    for (int j = 0; j < 64; ++j){
      float e = f1 + f2s[j]; e = (e > 0.f) ? e : ALPHA*e;
      unsigned bit = (j < 32) ? ((m0 >> j) & 1u) : ((m1 >> (j-32)) & 1u);
      e = bit ? e : NEGV;
      s += __expf(e - m);
    }
    const float inv = 1.f / s;
#pragma unroll
    for (int j = 0; j < 64; ++j){
      float e = f1 + f2s[j]; e = (e > 0.f) ? e : ALPHA*e;
      unsigned bit = (j < 32) ? ((m0 >> j) & 1u) : ((m1 >> (j-32)) & 1u);
      e = bit ? e : NEGV;
      attT[j][r] = __expf(e - m) * inv;
    }
  }
  __syncthreads();
  const int c = tid & 255, ih = tid >> 8;      // ih: 32-row half of output
  float acc[32];
#pragma unroll
  for (int i = 0; i < 32; ++i) acc[i] = 0.f;
#pragma unroll 2
  for (int j = 0; j < 64; ++j){
    float w = Wh[j*256 + c];                   // coalesced, L2-hot
    const float* ar = &attT[j][ih*32];         // broadcast b128 (16B-aligned)
#pragma unroll
    for (int i = 0; i < 32; ++i) acc[i] = fmaf(ar[i], w, acc[i]);
  }
  float* o = Fat + n*16384;
#pragma unroll
  for (int i = 0; i < 32; ++i) o[(ih*32 + i)*256 + c] = acc[i];
}

// ---- k5: partial Gi0 = cat_seg @ Wih0_seg^T. grid 768 = s*256 + n, block 256 ----
// v5 = R1 skeleton (gl2lds dbuf, vmcnt(5)) + k-split compute mapping.
// Thread = (b: 8x12-gate group, kg: k-half, ta: 16 t-quads); acc[12][4];
// k-halves reduced once at the end via LDS (reuses wl). Per kt: 48 W + 16 cat
// b128 reads feed 768 FMA (64 reads vs R1's 112). Cat source-swizzled with
// quad ^ ((row>>2)&7) so stride-4-row reads are 4-way max; W reads 2-way free.
__global__ __launch_bounds__(256) void k5_gi0(const float* __restrict__ Fat,
                                              const float* __restrict__ TatT,
                                              const float* __restrict__ x,
                                              const float* __restrict__ Wih0,
                                              float* __restrict__ P0,
                                              float* __restrict__ P1,
                                              float* __restrict__ P2){
  const int n = blockIdx.x & 255, s = blockIdx.x >> 8;
  const int tid = threadIdx.x;
  const int l = tid & 63, w = tid >> 6;        // lane, wave
  const int b = tid >> 5;                      // gate group 0..7 (12 gates each)
  const int kg = (tid >> 4) & 1;               // k-half within kt
  const int ta = tid & 15;                     // t-quad 0..15
  __shared__ float cl[2][2048];                // cat [64 t][32 k] swizzled, dbuf
  __shared__ float wl[2][3072];                // W  [96 g][32 k] linear,  dbuf
  const float* src = (s == 0) ? (Fat + n*16384)
                   : (s == 1) ? (TatT + n*16384)
                              : (x + n*16384);
  const float* Wseg = Wih0 + (size_t)n*73728 + s*256;
  // staging lane mapping: wave w stages cat rows 16w..16w+15, W rows 24w..24w+23
  const int lr = l >> 3, lc = l & 7;
  const int sc0 = lc ^ ((4*w + (lr >> 2)) & 7);      // swizzle, rows 16w+lr
  const int sc1 = lc ^ ((4*w + 2 + (lr >> 2)) & 7);  // swizzle, rows 16w+8+lr
  const float* cg0 = src + (16*w + lr)*256 + sc0*4;
  const float* cg1 = src + (16*w + 8 + lr)*256 + sc1*4;
  const float* wg0 = Wseg + (size_t)(24*w + lr)*768 + lc*4;
  const float* wg1 = wg0 + (size_t)8*768;
  const float* wg2 = wg0 + (size_t)16*768;

#define K5_STAGE(BF, K0) do {                       \
    gl2lds16(cg0 + (K0), &cl[BF][512*w]);           \
    gl2lds16(cg1 + (K0), &cl[BF][512*w + 256]);     \
    gl2lds16(wg0 + (K0), &wl[BF][768*w]);           \
    gl2lds16(wg1 + (K0), &wl[BF][768*w + 256]);     \
    gl2lds16(wg2 + (K0), &wl[BF][768*w + 512]);     \
  } while (0)

  float acc[12][4];
#pragma unroll
  for (int gi = 0; gi < 12; ++gi)
#pragma unroll
    for (int r = 0; r < 4; ++r) acc[gi][r] = 0.f;

  int bf = 0;
  K5_STAGE(0, 0);
  const int t7 = ta & 7;
#pragma unroll 1
  for (int kt = 0; kt < 8; ++kt){
    if (kt < 7){
      K5_STAGE(bf ^ 1, (kt + 1) * 32);
      asm volatile("s_waitcnt vmcnt(5)" ::: "memory");  // current tile landed
    } else {
      asm volatile("s_waitcnt vmcnt(0)" ::: "memory");
    }
    __builtin_amdgcn_s_barrier();
    const float* wb = &wl[bf][b*384 + kg*16];
    const float* cb = &cl[bf][ta*128];                  // row ta*4
#pragma unroll
    for (int k4 = 0; k4 < 4; ++k4){
      const int q4 = (((kg*4 + k4) ^ t7)) * 4;          // swizzled quad offset
      const float4 c0 = *(const float4*)&cb[0*32 + q4];
      const float4 c1 = *(const float4*)&cb[1*32 + q4];
      const float4 c2 = *(const float4*)&cb[2*32 + q4];
      const float4 c3 = *(const float4*)&cb[3*32 + q4];
#pragma unroll
      for (int gi = 0; gi < 12; ++gi){
        const float4 wv = *(const float4*)&wb[gi*32 + k4*4];
        float a0 = acc[gi][0], a1 = acc[gi][1], a2 = acc[gi][2], a3 = acc[gi][3];
        a0 = fmaf(wv.x, c0.x, a0); a1 = fmaf(wv.x, c1.x, a1);
        a2 = fmaf(wv.x, c2.x, a2); a3 = fmaf(wv.x, c3.x, a3);
        a0 = fmaf(wv.y, c0.y, a0); a1 = fmaf(wv.y, c1.y, a1);
        a2 = fmaf(wv.y, c2.y, a2); a3 = fmaf(wv.y, c3.y, a3);
        a0 = fmaf(wv.z, c0.z, a0); a1 = fmaf(wv.z, c1.z, a1);
        a2 = fmaf(wv.z, c2.z, a2); a3 = fmaf(wv.z, c3.z, a3);
        a0 = fmaf(wv.w, c0.w, a0); a1 = fmaf(wv.w, c1.w, a1);
        a2 = fmaf(wv.w, c2.w, a2); a3 = fmaf(wv.w, c3.w, a3);
        acc[gi][0] = a0; acc[gi][1] = a1; acc[gi][2] = a2; acc[gi][3] = a3;
      }
    }
    __builtin_amdgcn_s_barrier();
    bf ^= 1;
  }
#undef K5_STAGE
  // ---- cross-k-half reduce via LDS (wl = 6144 floats, free now) ----
  const int idx128 = b*16 + ta;
  float* red = &wl[0][0];
  if (kg == 1){
#pragma unroll
    for (int gi = 0; gi < 12; ++gi)
      *(float4*)&red[idx128*48 + gi*4] =
          make_float4(acc[gi][0], acc[gi][1], acc[gi][2], acc[gi][3]);
  }
  __syncthreads();
  if (kg == 0){
#pragma unroll
    for (int gi = 0; gi < 12; ++gi){
      const float4 v = *(const float4*)&red[idx128*48 + gi*4];
      acc[gi][0] += v.x; acc[gi][1] += v.y; acc[gi][2] += v.z; acc[gi][3] += v.w;
    }
    float* o = (s == 0) ? (P0 + n*16384)
             : (s == 1) ? (P1 + n*16384)
                        : (P2 + n*8192);
#pragma unroll
    for (int r = 0; r < 4; ++r){
      const int t = ta*4 + r;
#pragma unroll
      for (int qq = 0; qq < 3; ++qq)
        *(float4*)&o[t*96 + b*12 + qq*4] =
            make_float4(acc[4*qq][r], acc[4*qq+1][r], acc[4*qq+2][r], acc[4*qq+3][r]);
    }
  }
}

// ---- k6: 2-layer GRU, wave-pipelined. block 128 = wave0 (layer0) + wave1
// (layer1, one step behind). Handoff via double-buffered 32-float LDS slots.
__global__ __launch_bounds__(128) void k6_gru(const float* __restrict__ G0,
                                              const float* __restrict__ G1,
                                              const float* __restrict__ G2,
                                              const float* __restrict__ Hpre,
                                              const float* __restrict__ Whh0,
                                              const float* __restrict__ bih0,
                                              const float* __restrict__ bhh0,
                                              const float* __restrict__ Wih1,
                                              const float* __restrict__ Whh1,
                                              const float* __restrict__ bih1,
                                              const float* __restrict__ bhh1,
                                              const float* __restrict__ fc1w,
                                              const float* __restrict__ fc1b,
                                              const float* __restrict__ fc2w,
                                              const float* __restrict__ fc2b,
                                              const float* __restrict__ fc3w,
                                              const float* __restrict__ fc3b,
                                              float* __restrict__ ct,
                                              float* __restrict__ dout){
  const int n = blockIdx.x, tid = threadIdx.x;
  const int wid = tid >> 6, l = tid & 63;
  const int g2 = l & 31, co = (l >> 5) * 16;
  __shared__ float ginS[6144];                 // 24 KB summed gate inputs [t][96]
  __shared__ float h0buf[2][32];
  __shared__ float h1buf[2][32];
  __shared__ float hist[64][33];
  __shared__ float Wst[32][33];
  __shared__ float b1s[32], b2s[32], w3s[32];
  // ---- stage gin = G0+G1+G2 (128 threads, 12 float4 each) ----
  {
    const float4* p0 = (const float4*)(G0 + n*16384);
    const float4* p1 = (const float4*)(G1 + n*16384);
    const float4* p2 = (const float4*)(G2 + n*8192);
    float4* gs = (float4*)ginS;
#pragma unroll
    for (int j = 0; j < 12; ++j){
      int idx = j*128 + tid;
      float4 a = p0[idx], b = p1[idx], c = p2[idx];
      gs[idx] = make_float4(a.x+b.x+c.x, a.y+b.y+c.y, a.z+b.z+c.z, a.w+b.w+c.w);
    }
  }
  // ---- FC-head staging ----
  if (tid < 32){
    b1s[tid] = fc1b[n*32 + tid];
    b2s[tid] = fc2b[n*32 + tid];
    w3s[tid] = fc3w[n*32 + tid];
  }
  for (int idx = tid; idx < 1024; idx += 128) Wst[idx>>5][idx&31] = fc1w[n*1024 + idx];
  // ---- per-wave weights (wave0: Whh0; wave1: Wih1 + Whh1) ----
  float wr_[16], wz_[16], wn_[16];
  float ur_[16], uz_[16], un_[16];
  {
    const float* WA = (wid == 0) ? (Whh0 + n*3072) : (Wih1 + n*3072);
#pragma unroll
    for (int q = 0; q < 4; ++q){
      float4 v;
      v = *(const float4*)(WA + g2*32 + co + 4*q);       wr_[4*q]=v.x; wr_[4*q+1]=v.y; wr_[4*q+2]=v.z; wr_[4*q+3]=v.w;
      v = *(const float4*)(WA + (32+g2)*32 + co + 4*q);  wz_[4*q]=v.x; wz_[4*q+1]=v.y; wz_[4*q+2]=v.z; wz_[4*q+3]=v.w;
      v = *(const float4*)(WA + (64+g2)*32 + co + 4*q);  wn_[4*q]=v.x; wn_[4*q+1]=v.y; wn_[4*q+2]=v.z; wn_[4*q+3]=v.w;
    }
    if (wid == 1){
      const float* WB = Whh1 + n*3072;
#pragma unroll
      for (int q = 0; q < 4; ++q){
        float4 v;
        v = *(const float4*)(WB + g2*32 + co + 4*q);       ur_[4*q]=v.x; ur_[4*q+1]=v.y; ur_[4*q+2]=v.z; ur_[4*q+3]=v.w;
        v = *(const float4*)(WB + (32+g2)*32 + co + 4*q);  uz_[4*q]=v.x; uz_[4*q+1]=v.y; uz_[4*q+2]=v.z; uz_[4*q+3]=v.w;
        v = *(const float4*)(WB + (64+g2)*32 + co + 4*q);  un_[4*q]=v.x; un_[4*q+1]=v.y; un_[4*q+2]=v.z; un_[4*q+3]=v.w;
      }
    }
  }
  const float* bip = (wid == 0) ? bih0 : bih1;
  const float* bhp = (wid == 0) ? bhh0 : bhh1;
  const float br = bip[n*96 + g2], bz = bip[n*96 + 32 + g2], bn = bip[n*96 + 64 + g2];
  const float cr = bhp[n*96 + g2], cz = bhp[n*96 + 32 + g2], cn = bhp[n*96 + 64 + g2];
  // ---- initial state ----
  const float* hp = (wid == 0) ? (Hpre + n*32) : (Hpre + 8192 + n*32);
  float hown = hp[g2];
  float hs[16];
#pragma unroll
  for (int q = 0; q < 4; ++q){
    float4 v = *(const float4*)&hp[co + 4*q];
    hs[4*q]=v.x; hs[4*q+1]=v.y; hs[4*q+2]=v.z; hs[4*q+3]=v.w;
  }
  // ---- pipelined slot loop: wave0 computes h0(s) for s<64; wave1 h1(s-1) ----
  for (int s = 0; s < 65; ++s){
    __syncthreads();
    if (wid == 0){
      if (s < 64){
        const float gr = ginS[s*96 + g2], gz = ginS[s*96 + 32 + g2], gn = ginS[s*96 + 64 + g2];
        if (s > 0){
#pragma unroll
          for (int q = 0; q < 4; ++q){
            float4 v = *(const float4*)&h0buf[(s-1)&1][co + 4*q];
            hs[4*q]=v.x; hs[4*q+1]=v.y; hs[4*q+2]=v.z; hs[4*q+3]=v.w;
          }
        }
        float pr = 0.f, pz = 0.f, pn = 0.f;
#pragma unroll
        for (int j = 0; j < 16; ++j){
          pr = fmaf(wr_[j], hs[j], pr);
          pz = fmaf(wz_[j], hs[j], pz);
          pn = fmaf(wn_[j], hs[j], pn);
        }
        pr += __shfl_xor(pr, 32);
        pz += __shfl_xor(pz, 32);
        pn += __shfl_xor(pn, 32);
        const float r = sigf(gr + br + pr + cr);
        const float z = sigf(gz + bz + pz + cz);
        const float nn = tanhfa(gn + bn + r*(pn + cn));
        hown = (1.f - z)*nn + z*hown;
        if (l < 32) h0buf[s & 1][g2] = hown;
      }
    } else {
      if (s >= 1){
        const int t = s - 1;
        if (s > 1){
#pragma unroll
          for (int q = 0; q < 4; ++q){
            float4 v = *(const float4*)&h1buf[(s-1)&1][co + 4*q];
            hs[4*q]=v.x; hs[4*q+1]=v.y; hs[4*q+2]=v.z; hs[4*q+3]=v.w;
          }
        }
        float hx[16];
#pragma unroll
        for (int q = 0; q < 4; ++q){
          float4 v = *(const float4*)&h0buf[(s-1)&1][co + 4*q];
          hx[4*q]=v.x; hx[4*q+1]=v.y; hx[4*q+2]=v.z; hx[4*q+3]=v.w;
        }
        float qr = 0.f, qz = 0.f, qn = 0.f, sr = 0.f, sz = 0.f, sn = 0.f;
#pragma unroll
        for (int j = 0; j < 16; ++j){
          qr = fmaf(wr_[j], hx[j], qr);  sr = fmaf(ur_[j], hs[j], sr);
          qz = fmaf(wz_[j], hx[j], qz);  sz = fmaf(uz_[j], hs[j], sz);
          qn = fmaf(wn_[j], hx[j], qn);  sn = fmaf(un_[j], hs[j], sn);
        }
        float vr = qr + sr; vr += __shfl_xor(vr, 32);
        float vz = qz + sz; vz += __shfl_xor(vz, 32);
        qn += __shfl_xor(qn, 32);
        sn += __shfl_xor(sn, 32);
        const float r1 = sigf(vr + br + cr);
        const float z1 = sigf(vz + bz + cz);
        const float n1 = tanhfa(qn + bn + r1*(sn + cn));
        hown = (1.f - z1)*n1 + z1*hown;
        if (l < 32){ h1buf[s & 1][g2] = hown; hist[t][g2] = hown; }
      }
    }
  }
  if (wid == 0 && l < 32) dout[16384 + n*32 + g2] = hown;
  if (wid == 1 && l < 32) dout[16384 + 8192 + n*32 + g2] = hown;
  __syncthreads();
  // ---- fused FC head on first 64 threads (sensor = tid) ----
  float r1a[32];
  if (tid < 64){
    float hr[32];
#pragma unroll
    for (int k = 0; k < 32; ++k) hr[k] = hist[tid][k];
#pragma unroll
    for (int k = 0; k < 32; ++k){
      float a0=0.f,a1=0.f,a2=0.f,a3=0.f;
#pragma unroll
      for (int q = 0; q < 32; q += 4){
        a0 = fmaf(hr[q],   Wst[k][q],   a0);
        a1 = fmaf(hr[q+1], Wst[k][q+1], a1);
        a2 = fmaf(hr[q+2], Wst[k][q+2], a2);
        a3 = fmaf(hr[q+3], Wst[k][q+3], a3);
      }
      float v = b1s[k] + ((a0+a1)+(a2+a3));
      r1a[k] = v > 0.f ? v : 0.f;
    }
  }
  __syncthreads();
  for (int idx = tid; idx < 1024; idx += 128) Wst[idx>>5][idx&31] = fc2w[n*1024 + idx];
  __syncthreads();
  if (tid < 64){
    float r2a[32];
#pragma unroll
    for (int k = 0; k < 32; ++k){
      float a0=0.f,a1=0.f,a2=0.f,a3=0.f;
#pragma unroll
      for (int q = 0; q < 32; q += 4){
        a0 = fmaf(r1a[q],   Wst[k][q],   a0);
        a1 = fmaf(r1a[q+1], Wst[k][q+1], a1);
        a2 = fmaf(r1a[q+2], Wst[k][q+2], a2);
        a3 = fmaf(r1a[q+3], Wst[k][q+3], a3);
      }
      float v = b2s[k] + ((a0+a1)+(a2+a3));
      r2a[k] = v > 0.f ? v : 0.f;
    }
    float v = fc3b[n];
#pragma unroll
    for (int k = 0; k < 32; ++k) v = fmaf(r2a[k], w3s[k], v);
    ct[n*64 + tid] = v;
  }
}

// ---- k8a: Wh (transposed) + f1/f2 for out & out1. grid 8 = gat*4 + row-quarter ----
__global__ __launch_bounds__(256) void k8a(const float* __restrict__ ct,
                                           const float* __restrict__ W0,
                                           const float* __restrict__ a0,
                                           const float* __restrict__ W1,
                                           const float* __restrict__ a1,
                                           float* __restrict__ WhABt,
                                           float* __restrict__ OF1,
                                           float* __restrict__ OF2){
  const int gat = blockIdx.x >> 2, rq = blockIdx.x & 3, r0 = rq*64;
  const int tid = threadIdx.x;
  const int ii = tid & 63, cq = tid >> 6;
  __shared__ float ctl[64][65];
  __shared__ float Wl[64][68];
  __shared__ float a1s[64], a2s[64];
  __shared__ float red[64][4][2];
  const float* W = gat ? W1 : W0;
  const float* aa = gat ? a1 : a0;
  for (int idx = tid; idx < 4096; idx += 256){
    int i2 = idx >> 6, k = idx & 63;
    ctl[i2][k] = ct[(r0 + i2)*64 + k];
  }
  for (int idx = tid; idx < 4096; idx += 256){
    int k = idx >> 6, c = idx & 63;
    Wl[k][c] = W[k*64 + c];
  }
  if (tid < 64){ a1s[tid] = aa[tid]; a2s[tid] = aa[64 + tid]; }
  __syncthreads();
  float acc[16];
#pragma unroll
  for (int c = 0; c < 16; ++c) acc[c] = 0.f;
#pragma unroll 2
  for (int k = 0; k < 64; ++k){
    float v = ctl[ii][k];
    const float* wr = &Wl[k][cq*16];
#pragma unroll
    for (int c = 0; c < 16; ++c) acc[c] = fmaf(v, wr[c], acc[c]);
  }
  float p1 = 0.f, p2 = 0.f;
#pragma unroll
  for (int c = 0; c < 16; ++c){
    p1 = fmaf(acc[c], a1s[cq*16 + c], p1);
    p2 = fmaf(acc[c], a2s[cq*16 + c], p2);
  }
  red[ii][cq][0] = p1; red[ii][cq][1] = p2;
  float* o = WhABt + gat*16384;
#pragma unroll
  for (int c = 0; c < 16; ++c) o[(cq*16 + c)*256 + r0 + ii] = acc[c];
  __syncthreads();
  if (cq == 0){
    OF1[gat*256 + r0 + ii] = red[ii][0][0] + red[ii][1][0] + red[ii][2][0] + red[ii][3][0];
    OF2[gat*256 + r0 + ii] = red[ii][0][1] + red[ii][1][1] + red[ii][2][1] + red[ii][3][1];
  }
}

// ---- k8b: out/out1 attention, single-pass online softmax. grid 8 ----
__global__ __launch_bounds__(256) void k8b(const float* __restrict__ WhABt,
                                           const float* __restrict__ OF1,
                                           const float* __restrict__ OF2,
                                           const unsigned* __restrict__ maskA,
                                           float* __restrict__ OUTT){
  const int gat = blockIdx.x >> 2, c0 = (blockIdx.x & 3) * 16;
  const int i = threadIdx.x;
  __shared__ float wt[4096];                   // [16 c][256 j]
  __shared__ float f2s[256];
  __shared__ float wmax[4];
  {
    const int w = i >> 6, l = i & 63;
    const float* src = WhABt + gat*16384 + c0*256 + w*1024 + l*4;
    float* dst = &wt[w*1024];
#pragma unroll
    for (int r = 0; r < 4; ++r) gl2lds16(src + r*256, dst + r*256);
  }
  const float f1  = OF1[gat*256 + i];
  const float f2v = OF2[gat*256 + i];
  f2s[i] = f2v;
  unsigned mw[8];
#pragma unroll
  for (int w = 0; w < 8; ++w) mw[w] = maskA[i*8 + w];
  float wm = f2v;
#pragma unroll
  for (int d = 1; d < 64; d <<= 1) wm = fmaxf(wm, __shfl_xor(wm, d));
  if ((i & 63) == 0) wmax[i >> 6] = wm;
  asm volatile("s_waitcnt vmcnt(0)" ::: "memory");
  __syncthreads();
  const float mb = fmaxf(fmaxf(wmax[0], wmax[1]), fmaxf(wmax[2], wmax[3]));
  const float tm = f1 + mb;
  const float m  = (tm > 0.f) ? tm : ALPHA*tm;
  float acc[16];
#pragma unroll
  for (int c = 0; c < 16; ++c) acc[c] = 0.f;
  float s = 0.f;
#pragma unroll 2
  for (int jb = 0; jb < 64; ++jb){
    const float4 f2q = *(const float4*)&f2s[jb*4];
    const unsigned mk = mw[jb >> 3];
    const int sh = (jb & 7) * 4;
    float t0 = f1 + f2q.x; t0 = (t0 > 0.f) ? t0 : ALPHA*t0;
    float t1 = f1 + f2q.y; t1 = (t1 > 0.f) ? t1 : ALPHA*t1;
    float t2 = f1 + f2q.z; t2 = (t2 > 0.f) ? t2 : ALPHA*t2;
    float t3 = f1 + f2q.w; t3 = (t3 > 0.f) ? t3 : ALPHA*t3;
    const float e0 = ((mk >> (sh+0)) & 1u) ? __expf(t0 - m) : 0.f;
    const float e1 = ((mk >> (sh+1)) & 1u) ? __expf(t1 - m) : 0.f;
    const float e2 = ((mk >> (sh+2)) & 1u) ? __expf(t2 - m) : 0.f;
    const float e3 = ((mk >> (sh+3)) & 1u) ? __expf(t3 - m) : 0.f;
    s += (e0 + e1) + (e2 + e3);
#pragma unroll
    for (int c = 0; c < 16; ++c){
      const float4 wv = *(const float4*)&wt[c*256 + jb*4];
      acc[c] = fmaf(e0, wv.x, fmaf(e1, wv.y, fmaf(e2, wv.z, fmaf(e3, wv.w, acc[c]))));
    }
  }
  const float inv = (s > 0.f) ? __builtin_amdgcn_rcpf(s) : 0.f;
#pragma unroll
  for (int c = 0; c < 16; ++c) OUTT[gat*16384 + (c0+c)*256 + i] = acc[c] * inv;
}

// ---- k8c: Wh2 (transposed) + F1B/F2B. grid 8 = 32-row chunks ----
__global__ __launch_bounds__(256) void k8c(const float* __restrict__ OUTT,
                                           const float* __restrict__ W2,
                                           const float* __restrict__ a2,
                                           float* __restrict__ Wh2,
                                           float* __restrict__ F1B,
                                           float* __restrict__ F2B){
  const int r0 = blockIdx.x * 32;
  const int tid = threadIdx.x;
  const int ii = tid & 31, cq = tid >> 5;      // 8 groups x 8 cols
  __shared__ float W2l[128][68];
  __shared__ float a1s[64], a2s[64];
  __shared__ float red[32][8][2];
  for (int idx = tid; idx < 8192; idx += 256){
    int k = idx >> 6, c = idx & 63;
    W2l[k][c] = W2[k*64 + c];
  }
  if (tid < 64){ a1s[tid] = a2[tid]; a2s[tid] = a2[64 + tid]; }
  __syncthreads();
  float acc[8];
#pragma unroll
  for (int c = 0; c < 8; ++c) acc[c] = 0.f;
#pragma unroll 2
  for (int k = 0; k < 128; ++k){
    float v = OUTT[(k >> 6)*16384 + (k & 63)*256 + r0 + ii];
    const float* wr = &W2l[k][cq*8];
#pragma unroll
    for (int c = 0; c < 8; ++c) acc[c] = fmaf(v, wr[c], acc[c]);
  }
  float p1 = 0.f, p2 = 0.f;
#pragma unroll
  for (int c = 0; c < 8; ++c){
    p1 = fmaf(acc[c], a1s[cq*8 + c], p1);
    p2 = fmaf(acc[c], a2s[cq*8 + c], p2);
  }
  red[ii][cq][0] = p1; red[ii][cq][1] = p2;
#pragma unroll
  for (int c = 0; c < 8; ++c) Wh2[(cq*8 + c)*256 + r0 + ii] = acc[c];
  __syncthreads();
  if (cq == 0){
    float s1 = 0.f, s2 = 0.f;
#pragma unroll
    for (int q = 0; q < 8; ++q){ s1 += red[ii][q][0]; s2 += red[ii][q][1]; }
    F1B[r0 + ii] = s1; F2B[r0 + ii] = s2;
  }
}

// ---- k8d: final GAT -> d_out, single-pass online softmax. grid 4 ----
__global__ __launch_bounds__(256) void k8d(const float* __restrict__ Wh2,
                                           const float* __restrict__ F1B,
                                           const float* __restrict__ F2B,
                                           const unsigned* __restrict__ maskA,
                                           float* __restrict__ dOut){
  const int c0 = blockIdx.x * 16;
  const int i = threadIdx.x;
  __shared__ float wt[4096];                   // [16 c][256 j]
  __shared__ float f2s[256];
  __shared__ float wmax[4];
  {
    const int w = i >> 6, l = i & 63;
    const float* src = Wh2 + c0*256 + w*1024 + l*4;
    float* dst = &wt[w*1024];
#pragma unroll
    for (int r = 0; r < 4; ++r) gl2lds16(src + r*256, dst + r*256);
  }
  const float f1  = F1B[i];
  const float f2v = F2B[i];
  f2s[i] = f2v;
  unsigned mw[8];
#pragma unroll
  for (int w = 0; w < 8; ++w) mw[w] = maskA[i*8 + w];
  float wm = f2v;
#pragma unroll
  for (int d = 1; d < 64; d <<= 1) wm = fmaxf(wm, __shfl_xor(wm, d));
  if ((i & 63) == 0) wmax[i >> 6] = wm;
  asm volatile("s_waitcnt vmcnt(0)" ::: "memory");
  __syncthreads();
  const float mb = fmaxf(fmaxf(wmax[0], wmax[1]), fmaxf(wmax[2], wmax[3]));
  const float tm = f1 + mb;
  const float m  = (tm > 0.f) ? tm : ALPHA*tm;
  float acc[16];
#pragma unroll
  for (int c = 0; c < 16; ++c) acc[c] = 0.f;
  float s = 0.f;
#pragma unroll 2
  for (int jb = 0; jb < 64; ++jb){
    const float4 f2q = *(const float4*)&f2s[jb*4];
    const unsigned mk = mw[jb >> 3];
    const int sh = (jb & 7) * 4;
    float t0 = f1 + f2q.x; t0 = (t0 > 0.f) ? t0 : ALPHA*t0;
    float t1 = f1 + f2q.y; t1 = (t1 > 0.f) ? t1 : ALPHA*t1;
    float t2 = f1 + f2q.z; t2 = (t2 > 0.f) ? t2 : ALPHA*t2;
    float t3 = f1 + f2q.w; t3 = (t3 > 0.f) ? t3 : ALPHA*t3;
    const float e0 = ((mk >> (sh+0)) & 1u) ? __expf(t0 - m) : 0.f;
    const float e1 = ((mk >> (sh+1)) & 1u) ? __expf(t1 - m) : 0.f;
    const float e2 = ((mk >> (sh+2)) & 1u) ? __expf(t2 - m) : 0.f;
    const float e3 = ((mk >> (sh+3)) & 1u) ? __expf(t3 - m) : 0.f;
    s += (e0 + e1) + (e2 + e3);
#pragma unroll
    for (int c = 0; c < 16; ++c){
      const float4 wv = *(const float4*)&wt[c*256 + jb*4];
      acc[c] = fmaf(e0, wv.x, fmaf(e1, wv.y, fmaf(e2, wv.z, fmaf(e3, wv.w, acc[c]))));
    }
  }
  const float inv = (s > 0.f) ? __builtin_amdgcn_rcpf(s) : 0.f;
#pragma unroll
  for (int c = 0; c < 16; ++c) dOut[i*64 + c0 + c] = acc[c] * inv;
}

extern "C" void kernel_launch(void* const* d_in, const int* in_sizes, int n_in,
                              void* d_out, int out_size, void* d_ws, size_t ws_size,
                              hipStream_t stream){
  (void)in_sizes; (void)n_in; (void)out_size; (void)ws_size;
  const float* x     = (const float*)d_in[0];
  const float* Fadj  = (const float*)d_in[1];
  const float* Tadj  = (const float*)d_in[2];
  const float* adj   = (const float*)d_in[3];
  const float* Hpre  = (const float*)d_in[4];
  const float* FattW = (const float*)d_in[5];
  const float* Fatta = (const float*)d_in[6];
  const float* TattW = (const float*)d_in[7];
  const float* Tatta = (const float*)d_in[8];
  const float* Wih0  = (const float*)d_in[9];
  const float* Whh0  = (const float*)d_in[10];
  const float* bih0  = (const float*)d_in[11];
  const float* bhh0  = (const float*)d_in[12];
  const float* Wih1  = (const float*)d_in[13];
  const float* Whh1  = (const float*)d_in[14];
  const float* bih1  = (const float*)d_in[15];
  const float* bhh1  = (const float*)d_in[16];
  const float* fc1w  = (const float*)d_in[17];
  const float* fc1b  = (const float*)d_in[18];
  const float* fc2w  = (const float*)d_in[19];
  const float* fc2b  = (const float*)d_in[20];
  const float* fc3w  = (const float*)d_in[21];
  const float* fc3b  = (const float*)d_in[22];
  const float* oW    = (const float*)d_in[23];
  const float* oa    = (const float*)d_in[24];
  const float* o1W   = (const float*)d_in[25];
  const float* o1a   = (const float*)d_in[26];
  const float* o2W   = (const float*)d_in[27];
  const float* o2a   = (const float*)d_in[28];
  float* out = (float*)d_out;

  float* ws = (float*)d_ws;
  float* R0 = ws;
  float* R1 = ws + 4194304;
  float* R2 = ws + 8388608;
  unsigned* maskT = (unsigned*)R2;             // 524288 words
  float* Tf1p = R2 + 524288;                   // 2 x 65536
  float* Tf2p = R2 + 655360;                   // 2 x 65536
  unsigned* maskA = (unsigned*)(ws + 12582912);// 2048 words
  float* WhTt = R0;
  float* WhF  = R0;
  float* TatT = R1;
  float* Fat  = R2;
  float* P0 = R2;
  float* P1 = R1;
  float* P2 = R0;
  float* ctb   = R0 + 2097152;                 // above P2's span
  float* WhABt = R1 + 16384;
  float* OF1   = R1 + 49152;
  float* OF2   = R1 + 49664;
  float* OUTT  = R1 + 50176;
  float* WH2   = R1 + 82944;
  float* F1B   = R1 + 99328;
  float* F2B   = R1 + 99584;

  k_mask<<<1024, 256, 0, stream>>>(Tadj, maskT, 16777216);
  k_mask<<<32, 256, 0, stream>>>(adj, maskA, 65536);
  k3_wht<<<512, 256, 0, stream>>>(x, TattW, Tatta, WhTt, Tf1p, Tf2p);
  k4_tat<<<512, 256, 0, stream>>>(WhTt, Tf1p, Tf2p, maskT, TatT);
  k1_whf<<<512, 256, 0, stream>>>(x, FattW, WhF);
  k2_fat<<<256, 512, 0, stream>>>(WhF, Fatta, Fadj, Fat);
  k5_gi0<<<768, 256, 0, stream>>>(Fat, TatT, x, Wih0, P0, P1, P2);
  k6_gru<<<256, 128, 0, stream>>>(P0, P1, P2, Hpre, Whh0, bih0, bhh0, Wih1, Whh1, bih1, bhh1,
                                  fc1w, fc1b, fc2w, fc2b, fc3w, fc3b, ctb, out);
  k8a<<<8, 256, 0, stream>>>(ctb, oW, oa, o1W, o1a, WhABt, OF1, OF2);
  k8b<<<8, 256, 0, stream>>>(WhABt, OF1, OF2, maskA, OUTT);
  k8c<<<8, 256, 0, stream>>>(OUTT, o2W, o2a, WH2, F1B, F2B);
  k8d<<<4, 256, 0, stream>>>(WH2, F1B, F2B, maskA, out);
}